// Round 1
// baseline (127.626 us; speedup 1.0000x reference)
//
#include <hip/hip_runtime.h>
#include <math.h>

#define BATCH 4096
#define DIM 128
#define NCLS 100
#define MARGIN 0.3f

typedef __attribute__((ext_vector_type(8))) short short8;
typedef __attribute__((ext_vector_type(4))) float f32x4;

// ---- bf16 helpers (bit-level, RNE) — avoid hip_bf16.h API drift ----
__device__ __forceinline__ unsigned short f2bf(float f) {
    unsigned int u = __float_as_uint(f);
    unsigned int r = (u + 0x7FFFu + ((u >> 16) & 1u)) >> 16;
    return (unsigned short)r;
}
__device__ __forceinline__ float bf2f(unsigned short b) {
    return __uint_as_float(((unsigned int)b) << 16);
}

// K1: blocks 0..255: convert emb->bf16 + sq (from rounded values, so diag d2==0)
//     blocks 256..271: transpose fc_w [100][128] -> wT [128][100]
__global__ __launch_bounds__(256) void prep_kernel(
        const float* __restrict__ emb, const float* __restrict__ fcw,
        unsigned short* __restrict__ ebf, float* __restrict__ sq,
        float* __restrict__ wT) {
    int bid = blockIdx.x, tid = threadIdx.x;
    if (bid < 256) {
        int wave = tid >> 6, lane = tid & 63;
        #pragma unroll
        for (int r = 0; r < 4; ++r) {
            int row = bid * 16 + wave * 4 + r;
            const float2* src = reinterpret_cast<const float2*>(emb + row * DIM);
            float2 xy = src[lane];
            unsigned short b0 = f2bf(xy.x), b1 = f2bf(xy.y);
            float y0 = bf2f(b0), y1 = bf2f(b1);
            reinterpret_cast<unsigned int*>(ebf + row * DIM)[lane] =
                ((unsigned int)b1 << 16) | (unsigned int)b0;
            float acc = y0 * y0 + y1 * y1;
            #pragma unroll
            for (int off = 1; off < 64; off <<= 1) acc += __shfl_xor(acc, off, 64);
            if (lane == 0) sq[row] = acc;
        }
    } else {
        int idx = (bid - 256) * 256 + tid;           // 4096 threads
        for (int k = idx; k < NCLS * DIM; k += 4096) {
            int c = k >> 7, d = k & 127;
            wT[d * NCLS + c] = fcw[k];
        }
    }
}

// K2: cross-entropy per row. 8 rows/block, 128 threads.
__global__ __launch_bounds__(128) void ce_kernel(
        const float* __restrict__ emb, const int* __restrict__ labels,
        const float* __restrict__ wT, const float* __restrict__ fcb,
        float* __restrict__ ce) {
    __shared__ float e[8][DIM];
    __shared__ float lg[8][DIM];
    int tid = threadIdx.x;
    int R0 = blockIdx.x * 8;
    for (int idx = tid; idx < 8 * DIM; idx += 128)
        e[idx >> 7][idx & 127] = emb[R0 * DIM + idx];
    __syncthreads();
    if (tid < NCLS) {
        float acc[8];
        float b = fcb[tid];
        #pragma unroll
        for (int r = 0; r < 8; ++r) acc[r] = b;
        for (int d = 0; d < DIM; ++d) {
            float w = wT[d * NCLS + tid];
            #pragma unroll
            for (int r = 0; r < 8; ++r) acc[r] = fmaf(e[r][d], w, acc[r]);
        }
        #pragma unroll
        for (int r = 0; r < 8; ++r) lg[r][tid] = acc[r];
    } else {
        #pragma unroll
        for (int r = 0; r < 8; ++r) lg[r][tid] = -INFINITY;
    }
    __syncthreads();
    int wave = tid >> 6, lane = tid & 63;
    for (int r = wave; r < 8; r += 2) {
        float x0 = lg[r][lane], x1 = lg[r][lane + 64];
        float m = fmaxf(x0, x1);
        #pragma unroll
        for (int off = 1; off < 64; off <<= 1) m = fmaxf(m, __shfl_xor(m, off, 64));
        float s = expf(x0 - m) + expf(x1 - m);   // -inf pads -> 0
        #pragma unroll
        for (int off = 1; off < 64; off <<= 1) s += __shfl_xor(s, off, 64);
        if (lane == 0) {
            int lab = labels[R0 + r];
            ce[R0 + r] = (m + logf(s)) - lg[r][lab];
        }
    }
}

// K3: pairwise via bf16 MFMA, fused hardest-pos/neg over squared distances.
// Grid: 256 blocks = (64 row-groups of 64 rows) x (4 col-chunks of 1024).
// Each wave: 16 rows; A-fragments live in registers for the whole kernel.
__global__ __launch_bounds__(256) void pairwise_kernel(
        const unsigned short* __restrict__ ebf, const float* __restrict__ sq,
        const int* __restrict__ labels,
        float* __restrict__ appart, float* __restrict__ anpart) {
    int bid = blockIdx.x;
    int rowgrp = bid >> 2, chunk = bid & 3;
    int tid = threadIdx.x, wave = tid >> 6, lane = tid & 63;
    int rbase = rowgrp * 64 + wave * 16;
    int arow = rbase + (lane & 15);
    int koff = (lane >> 4) * 8;        // A[m=lane&15][k=quad*8+j], 4 k-steps of 32

    const short8* ap = reinterpret_cast<const short8*>(ebf + arow * DIM + koff);
    short8 a0 = ap[0];                  // k 0..31   (+koff within)
    short8 a1 = *reinterpret_cast<const short8*>(ebf + arow * DIM + 32 + koff);
    short8 a2 = *reinterpret_cast<const short8*>(ebf + arow * DIM + 64 + koff);
    short8 a3 = *reinterpret_cast<const short8*>(ebf + arow * DIM + 96 + koff);

    int labr[4];
    #pragma unroll
    for (int r = 0; r < 4; ++r) labr[r] = labels[rbase + (lane >> 4) * 4 + r];

    float rmax[4] = {-INFINITY, -INFINITY, -INFINITY, -INFINITY};
    float rmin[4] = { INFINITY,  INFINITY,  INFINITY,  INFINITY};

    int cbase0 = chunk * 1024;
    for (int ct = 0; ct < 64; ++ct) {
        int col = cbase0 + ct * 16 + (lane & 15);
        const unsigned short* bp = ebf + col * DIM + koff;
        short8 b0 = *reinterpret_cast<const short8*>(bp);
        short8 b1 = *reinterpret_cast<const short8*>(bp + 32);
        short8 b2 = *reinterpret_cast<const short8*>(bp + 64);
        short8 b3 = *reinterpret_cast<const short8*>(bp + 96);
        f32x4 c = {0.f, 0.f, 0.f, 0.f};
        c = __builtin_amdgcn_mfma_f32_16x16x32_bf16(a0, b0, c, 0, 0, 0);
        c = __builtin_amdgcn_mfma_f32_16x16x32_bf16(a1, b1, c, 0, 0, 0);
        c = __builtin_amdgcn_mfma_f32_16x16x32_bf16(a2, b2, c, 0, 0, 0);
        c = __builtin_amdgcn_mfma_f32_16x16x32_bf16(a3, b3, c, 0, 0, 0);
        float sqc = sq[col];
        int lc = labels[col];
        #pragma unroll
        for (int r = 0; r < 4; ++r) {
            float v = fmaf(c[r], -2.0f, sqc);      // sq_j - 2*dot  (sq_i added later)
            bool same = (lc == labr[r]);
            rmax[r] = same ? fmaxf(rmax[r], v) : rmax[r];
            rmin[r] = same ? rmin[r] : fminf(rmin[r], v);
        }
    }
    // reduce across the 16 lanes sharing the same rows (lane&15 = col slot)
    #pragma unroll
    for (int off = 1; off < 16; off <<= 1) {
        #pragma unroll
        for (int r = 0; r < 4; ++r) {
            rmax[r] = fmaxf(rmax[r], __shfl_xor(rmax[r], off, 64));
            rmin[r] = fminf(rmin[r], __shfl_xor(rmin[r], off, 64));
        }
    }
    if ((lane & 15) == 0) {
        int row0 = rbase + (lane >> 4) * 4;
        #pragma unroll
        for (int r = 0; r < 4; ++r) {
            appart[chunk * BATCH + row0 + r] = rmax[r];
            anpart[chunk * BATCH + row0 + r] = rmin[r];
        }
    }
}

// K4: combine 4 chunk-partials, sqrt, relu, mean; add CE mean; write scalar.
__global__ __launch_bounds__(256) void final_kernel(
        const float* __restrict__ sq, const float* __restrict__ appart,
        const float* __restrict__ anpart, const float* __restrict__ ce,
        float* __restrict__ out) {
    __shared__ float red[256];
    int tid = threadIdx.x;
    float acc = 0.f;
    for (int i = tid; i < BATCH; i += 256) {
        float m = appart[i], n = anpart[i];
        #pragma unroll
        for (int p = 1; p < 4; ++p) {
            m = fmaxf(m, appart[p * BATCH + i]);
            n = fminf(n, anpart[p * BATCH + i]);
        }
        float api = sqrtf(fmaxf(sq[i] + m, 1e-12f));
        float ani = sqrtf(fmaxf(sq[i] + n, 1e-12f));
        acc += fmaxf(api - ani + MARGIN, 0.f) + ce[i];
    }
    red[tid] = acc;
    __syncthreads();
    for (int s = 128; s > 0; s >>= 1) {
        if (tid < s) red[tid] += red[tid + s];
        __syncthreads();
    }
    if (tid == 0) out[0] = red[0] * (1.0f / BATCH);
}

extern "C" void kernel_launch(void* const* d_in, const int* in_sizes, int n_in,
                              void* d_out, int out_size, void* d_ws, size_t ws_size,
                              hipStream_t stream) {
    const float* emb    = (const float*)d_in[0];
    const int*   labels = (const int*)  d_in[1];
    const float* fcw    = (const float*)d_in[2];
    const float* fcb    = (const float*)d_in[3];
    float* out = (float*)d_out;

    char* ws = (char*)d_ws;
    unsigned short* ebf = (unsigned short*)(ws);                    // 1 MB
    float* sq     = (float*)(ws + (1u << 20));                      // 16 KB
    float* wT     = (float*)(ws + (1u << 20) + (16u << 10));        // 52 KB
    float* ce     = (float*)(ws + (1u << 20) + (80u << 10));        // 16 KB
    float* appart = (float*)(ws + (1u << 20) + (96u << 10));        // 64 KB
    float* anpart = (float*)(ws + (1u << 20) + (160u << 10));       // 64 KB

    prep_kernel<<<272, 256, 0, stream>>>(emb, fcw, ebf, sq, wT);
    ce_kernel<<<BATCH / 8, 128, 0, stream>>>(emb, labels, wT, fcb, ce);
    pairwise_kernel<<<256, 256, 0, stream>>>(ebf, sq, labels, appart, anpart);
    final_kernel<<<1, 256, 0, stream>>>(sq, appart, anpart, ce, out);
}

// Round 2
// 109.205 us; speedup vs baseline: 1.1687x; 1.1687x over previous
//
#include <hip/hip_runtime.h>
#include <math.h>

#define BATCH 4096
#define DIM 128
#define NCLS 100
#define MARGIN 0.3f

typedef __attribute__((ext_vector_type(8))) short short8;
typedef __attribute__((ext_vector_type(4))) float f32x4;

// ---- bf16 helpers (bit-level, RNE) ----
__device__ __forceinline__ unsigned short f2bf(float f) {
    unsigned int u = __float_as_uint(f);
    unsigned int r = (u + 0x7FFFu + ((u >> 16) & 1u)) >> 16;
    return (unsigned short)r;
}
__device__ __forceinline__ float bf2f(unsigned short b) {
    return __uint_as_float(((unsigned int)b) << 16);
}

// K1: blocks 0..255: convert emb->bf16 + sq (from rounded values, so diag d2==0).
//     blocks 256..257: convert fc_w -> bf16 wbf[112][128], zero-padded classes 100..111.
__global__ __launch_bounds__(256) void prep_kernel(
        const float* __restrict__ emb, const float* __restrict__ fcw,
        unsigned short* __restrict__ ebf, float* __restrict__ sq,
        unsigned short* __restrict__ wbf) {
    int bid = blockIdx.x, tid = threadIdx.x;
    if (bid < 256) {
        int wave = tid >> 6, lane = tid & 63;
        #pragma unroll
        for (int r = 0; r < 4; ++r) {
            int row = bid * 16 + wave * 4 + r;
            const float2* src = reinterpret_cast<const float2*>(emb + row * DIM);
            float2 xy = src[lane];
            unsigned short b0 = f2bf(xy.x), b1 = f2bf(xy.y);
            float y0 = bf2f(b0), y1 = bf2f(b1);
            reinterpret_cast<unsigned int*>(ebf + row * DIM)[lane] =
                ((unsigned int)b1 << 16) | (unsigned int)b0;
            float acc = y0 * y0 + y1 * y1;
            #pragma unroll
            for (int off = 1; off < 64; off <<= 1) acc += __shfl_xor(acc, off, 64);
            if (lane == 0) sq[row] = acc;
        }
    } else {
        int idx = (bid - 256) * 256 + tid;          // 512 threads total
        for (int k = idx; k < 112 * DIM; k += 512) {
            wbf[k] = (k < NCLS * DIM) ? f2bf(fcw[k]) : (unsigned short)0;
        }
    }
}

// K2 (fused): blocks 0..1023  -> pairwise hardest-pos/neg partials (16 col-chunks)
//             blocks 1024..1279 -> CE per 16 rows via MFMA logits + wave softmax
__global__ __launch_bounds__(256) void main_kernel(
        const unsigned short* __restrict__ ebf, const unsigned short* __restrict__ wbf,
        const float* __restrict__ sq, const int* __restrict__ labels,
        const float* __restrict__ fcb,
        float* __restrict__ appart, float* __restrict__ anpart,
        float* __restrict__ ce) {
    __shared__ float lg[16][128];
    int bid = blockIdx.x, tid = threadIdx.x;
    int wave = tid >> 6, lane = tid & 63;
    int lm = lane & 15, lq = lane >> 4;
    int koff = lq * 8;                 // frag: [idx=lane&15][k = lq*8 + j], 4 k-steps of 32

    if (bid < 1024) {
        // ---------------- pairwise ----------------
        int rowgrp = bid >> 4, chunk = bid & 15;
        int rbase = rowgrp * 64 + wave * 16;
        int arow = rbase + lm;
        const unsigned short* apt = ebf + arow * DIM + koff;
        short8 a0 = *reinterpret_cast<const short8*>(apt);
        short8 a1 = *reinterpret_cast<const short8*>(apt + 32);
        short8 a2 = *reinterpret_cast<const short8*>(apt + 64);
        short8 a3 = *reinterpret_cast<const short8*>(apt + 96);

        int labr[4];
        #pragma unroll
        for (int r = 0; r < 4; ++r) labr[r] = labels[rbase + lq * 4 + r];

        float rmax[4] = {-INFINITY, -INFINITY, -INFINITY, -INFINITY};
        float rmin[4] = { INFINITY,  INFINITY,  INFINITY,  INFINITY};

        int cbase = chunk * 256;
        #pragma unroll 4
        for (int ct = 0; ct < 16; ++ct) {
            int col = cbase + ct * 16 + lm;
            const unsigned short* bp = ebf + col * DIM + koff;
            short8 b0 = *reinterpret_cast<const short8*>(bp);
            short8 b1 = *reinterpret_cast<const short8*>(bp + 32);
            short8 b2 = *reinterpret_cast<const short8*>(bp + 64);
            short8 b3 = *reinterpret_cast<const short8*>(bp + 96);
            f32x4 c = {0.f, 0.f, 0.f, 0.f};
            c = __builtin_amdgcn_mfma_f32_16x16x32_bf16(a0, b0, c, 0, 0, 0);
            c = __builtin_amdgcn_mfma_f32_16x16x32_bf16(a1, b1, c, 0, 0, 0);
            c = __builtin_amdgcn_mfma_f32_16x16x32_bf16(a2, b2, c, 0, 0, 0);
            c = __builtin_amdgcn_mfma_f32_16x16x32_bf16(a3, b3, c, 0, 0, 0);
            float sqc = sq[col];
            int lc = labels[col];
            #pragma unroll
            for (int r = 0; r < 4; ++r) {
                float v = fmaf(c[r], -2.0f, sqc);     // sq_j - 2*dot (sq_i added later)
                bool same = (lc == labr[r]);
                rmax[r] = same ? fmaxf(rmax[r], v) : rmax[r];
                rmin[r] = same ? rmin[r] : fminf(rmin[r], v);
            }
        }
        #pragma unroll
        for (int off = 1; off < 16; off <<= 1) {
            #pragma unroll
            for (int r = 0; r < 4; ++r) {
                rmax[r] = fmaxf(rmax[r], __shfl_xor(rmax[r], off, 64));
                rmin[r] = fminf(rmin[r], __shfl_xor(rmin[r], off, 64));
            }
        }
        if (lm == 0) {
            int row0 = rbase + lq * 4;
            #pragma unroll
            for (int r = 0; r < 4; ++r) {
                appart[(row0 + r) * 16 + chunk] = rmax[r];
                anpart[(row0 + r) * 16 + chunk] = rmin[r];
            }
        }
    } else {
        // ---------------- cross-entropy ----------------
        int R0 = (bid - 1024) * 16;
        lg[tid >> 4][112 + (tid & 15)] = -INFINITY;   // pad cols 112..127

        int arow = R0 + lm;
        const unsigned short* apt = ebf + arow * DIM + koff;
        short8 a0 = *reinterpret_cast<const short8*>(apt);
        short8 a1 = *reinterpret_cast<const short8*>(apt + 32);
        short8 a2 = *reinterpret_cast<const short8*>(apt + 64);
        short8 a3 = *reinterpret_cast<const short8*>(apt + 96);

        // 7 class-tiles (112 padded classes) split over 4 waves
        for (int t = wave * 2; t < 7 && t < wave * 2 + 2; ++t) {
            int cls = t * 16 + lm;
            const unsigned short* bp = wbf + cls * DIM + koff;
            short8 b0 = *reinterpret_cast<const short8*>(bp);
            short8 b1 = *reinterpret_cast<const short8*>(bp + 32);
            short8 b2 = *reinterpret_cast<const short8*>(bp + 64);
            short8 b3 = *reinterpret_cast<const short8*>(bp + 96);
            f32x4 c = {0.f, 0.f, 0.f, 0.f};
            c = __builtin_amdgcn_mfma_f32_16x16x32_bf16(a0, b0, c, 0, 0, 0);
            c = __builtin_amdgcn_mfma_f32_16x16x32_bf16(a1, b1, c, 0, 0, 0);
            c = __builtin_amdgcn_mfma_f32_16x16x32_bf16(a2, b2, c, 0, 0, 0);
            c = __builtin_amdgcn_mfma_f32_16x16x32_bf16(a3, b3, c, 0, 0, 0);
            float bias = (cls < NCLS) ? fcb[cls] : -INFINITY;
            #pragma unroll
            for (int r = 0; r < 4; ++r)
                lg[lq * 4 + r][t * 16 + lm] = c[r] + bias;
        }
        __syncthreads();
        #pragma unroll
        for (int i = 0; i < 4; ++i) {
            int r = wave * 4 + i;
            float x0 = lg[r][lane], x1 = lg[r][lane + 64];
            float m = fmaxf(x0, x1);
            #pragma unroll
            for (int off = 1; off < 64; off <<= 1) m = fmaxf(m, __shfl_xor(m, off, 64));
            float s = expf(x0 - m) + expf(x1 - m);    // -inf pads -> 0
            #pragma unroll
            for (int off = 1; off < 64; off <<= 1) s += __shfl_xor(s, off, 64);
            if (lane == 0) {
                int lab = labels[R0 + r];
                ce[R0 + r] = (m + logf(s)) - lg[r][lab];
            }
        }
    }
}

// K3: combine 16 chunk-partials per row, sqrt, relu, + ce; block-reduce; atomicAdd.
__global__ __launch_bounds__(256) void final_kernel(
        const float* __restrict__ sq, const float* __restrict__ appart,
        const float* __restrict__ anpart, const float* __restrict__ ce,
        float* __restrict__ out) {
    __shared__ float red[256];
    int tid = threadIdx.x, bid = blockIdx.x;
    float acc = 0.f;
    #pragma unroll
    for (int rr = 0; rr < 2; ++rr) {
        int row = bid * 512 + rr * 256 + tid;
        const float4* ap = reinterpret_cast<const float4*>(appart + row * 16);
        const float4* an = reinterpret_cast<const float4*>(anpart + row * 16);
        float m = -INFINITY, n = INFINITY;
        #pragma unroll
        for (int p = 0; p < 4; ++p) {
            float4 a = ap[p];
            m = fmaxf(m, fmaxf(fmaxf(a.x, a.y), fmaxf(a.z, a.w)));
            float4 b = an[p];
            n = fminf(n, fminf(fminf(b.x, b.y), fminf(b.z, b.w)));
        }
        float api = sqrtf(fmaxf(sq[row] + m, 1e-12f));
        float ani = sqrtf(fmaxf(sq[row] + n, 1e-12f));
        acc += fmaxf(api - ani + MARGIN, 0.f) + ce[row];
    }
    red[tid] = acc;
    __syncthreads();
    for (int s = 128; s > 0; s >>= 1) {
        if (tid < s) red[tid] += red[tid + s];
        __syncthreads();
    }
    if (tid == 0) atomicAdd(out, red[0] * (1.0f / BATCH));
}

extern "C" void kernel_launch(void* const* d_in, const int* in_sizes, int n_in,
                              void* d_out, int out_size, void* d_ws, size_t ws_size,
                              hipStream_t stream) {
    const float* emb    = (const float*)d_in[0];
    const int*   labels = (const int*)  d_in[1];
    const float* fcw    = (const float*)d_in[2];
    const float* fcb    = (const float*)d_in[3];
    float* out = (float*)d_out;

    char* ws = (char*)d_ws;
    unsigned short* ebf = (unsigned short*)(ws);                 // 1 MB
    unsigned short* wbf = (unsigned short*)(ws + 1048576);       // 28 KB (pad to 32K)
    float* sq     = (float*)(ws + 1081344);                      // 16 KB
    float* ce     = (float*)(ws + 1097728);                      // 16 KB
    float* appart = (float*)(ws + 1114112);                      // 256 KB
    float* anpart = (float*)(ws + 1376256);                      // 256 KB

    hipMemsetAsync(out, 0, sizeof(float), stream);
    prep_kernel<<<258, 256, 0, stream>>>(emb, fcw, ebf, sq, wbf);
    main_kernel<<<1280, 256, 0, stream>>>(ebf, wbf, sq, labels, fcb, appart, anpart, ce);
    final_kernel<<<8, 256, 0, stream>>>(sq, appart, anpart, ce, out);
}